// Round 8
// baseline (787.408 us; speedup 1.0000x reference)
//
#include <hip/hip_runtime.h>
#include <math.h>

#define NN 100000
#define EE 1600000
#define BB 64
#define CAP 48   // max in-degree slots; deg ~ Binomial(1.6M,1e-5)≈Poisson(16); P(deg>=48)~2e-10

__device__ __forceinline__ float lrelu(float v) { return v > 0.f ? v : 0.2f * v; }

// ---------- temporal conv: x[N,1,35] -> h0[N,128] ----------
// 16 nodes/block x 16 threads/node; c1 via LDS; coalesced float4 epilogue
__global__ __launch_bounds__(256) void conv_kernel(
    const float* __restrict__ x,
    const float* __restrict__ w1, const float* __restrict__ b1,
    const float* __restrict__ w2, const float* __restrict__ b2,
    float* __restrict__ h0)
{
  __shared__ float s_x[16 * 35];
  __shared__ float s_c1[16 * 49];
  __shared__ float s_w2[16 * 49];
  __shared__ float s_w1[48], s_b1[16], s_b2[16];
  int tid = threadIdx.x;
  int n0 = blockIdx.x * 16;
  for (int i = tid; i < 16 * 35; i += 256) s_x[i] = x[(size_t)n0 * 35 + i];
  if (tid < 48) s_w1[tid] = w1[tid];
  if (tid < 16) { s_b1[tid] = b1[tid]; s_b2[tid] = b2[tid]; }
  for (int i = tid; i < 768; i += 256) s_w2[(i / 48) * 49 + (i % 48)] = w2[i];
  __syncthreads();

  int node = tid >> 4;
  int lane = tid & 15;
  const float* row = s_x + node * 35;
  float* c1n = s_c1 + node * 49;
  float acc8[8];

  for (int t = 0; t < 8; ++t) {
#pragma unroll
    for (int k = 0; k < 3; ++k) {
      int base = 4 * t + 2 * k;
      float a = s_b1[lane] + s_w1[lane * 3] * row[base]
                           + s_w1[lane * 3 + 1] * row[base + 1]
                           + s_w1[lane * 3 + 2] * row[base + 2];
      c1n[lane * 3 + k] = a > 0.f ? a : 0.f;
    }
    __syncthreads();
    float acc = s_b2[lane];
    const float* w2r = s_w2 + lane * 49;
#pragma unroll
    for (int i = 0; i < 48; ++i) acc += w2r[i] * c1n[i];
    acc8[t] = fmaxf(acc, 0.f);
    __syncthreads();
  }

  float* o = h0 + (size_t)(n0 + node) * 128 + lane * 8;
  float4 o0 = { acc8[0], acc8[1], acc8[2], acc8[3] };
  float4 o1 = { acc8[4], acc8[5], acc8[6], acc8[7] };
  *(float4*)o = o0;
  *(float4*)(o + 4) = o1;
}

// ---------- single-pass padded-CSR build: 4 edges/thread, vector loads ----------
__global__ void scatter_pad(const int* __restrict__ src, const int* __restrict__ dst,
                            const float* __restrict__ ea,
                            int* __restrict__ cursor, int2* __restrict__ pack)
{
  int i = blockIdx.x * blockDim.x + threadIdx.x;   // quad index; EE % 4 == 0
  if (i >= EE / 4) return;
  int4 s4 = ((const int4*)src)[i];
  int4 d4 = ((const int4*)dst)[i];
  float4 a4 = ((const float4*)ea)[i];
  int pos;
  pos = atomicAdd(cursor + d4.x, 1);
  if (pos < CAP) pack[(size_t)d4.x * CAP + pos] = make_int2(s4.x, __float_as_int(a4.x));
  pos = atomicAdd(cursor + d4.y, 1);
  if (pos < CAP) pack[(size_t)d4.y * CAP + pos] = make_int2(s4.y, __float_as_int(a4.y));
  pos = atomicAdd(cursor + d4.z, 1);
  if (pos < CAP) pack[(size_t)d4.z * CAP + pos] = make_int2(s4.z, __float_as_int(a4.z));
  pos = atomicAdd(cursor + d4.w, 1);
  if (pos < CAP) pack[(size_t)d4.w * CAP + pos] = make_int2(s4.w, __float_as_int(a4.w));
}

// ---------- dual GEMM as C = A @ [Wl|Wr]: 64x256 block tile, 8x8 thread tile ----------
__global__ __launch_bounds__(256) void gemm_dual(
    const float* __restrict__ A,
    const float* __restrict__ Wl, const float* __restrict__ Wr,
    float* __restrict__ Cl, float* __restrict__ Cr)
{
  __shared__ float sA[64][128];
  int tid = threadIdx.x;
  int row0 = blockIdx.x * 64;
  int nrows = NN - row0; if (nrows > 64) nrows = 64;
  for (int i = tid; i < nrows * 32; i += 256)
    ((float4*)sA)[i] = ((const float4*)(A + (size_t)row0 * 128))[i];
  __syncthreads();

  int tx = tid & 31;
  int ty = tid >> 5;
  const float* Wb = (tx < 16) ? Wl : Wr;
  float*       Cb = (tx < 16) ? Cl : Cr;
  int c0 = (tx & 15) * 8;

  float acc[8][8];
#pragma unroll
  for (int r = 0; r < 8; ++r)
#pragma unroll
    for (int c = 0; c < 8; ++c) acc[r][c] = 0.f;

  for (int k = 0; k < 128; k += 4) {
    float4 a[8];
#pragma unroll
    for (int r = 0; r < 8; ++r) a[r] = *(const float4*)&sA[ty * 8 + r][k];
#pragma unroll
    for (int kk = 0; kk < 4; ++kk) {
      float4 w0 = *(const float4*)&Wb[(k + kk) * 128 + c0];
      float4 w1 = *(const float4*)&Wb[(k + kk) * 128 + c0 + 4];
#pragma unroll
      for (int r = 0; r < 8; ++r) {
        float av = (kk == 0) ? a[r].x : (kk == 1) ? a[r].y : (kk == 2) ? a[r].z : a[r].w;
        acc[r][0] += av * w0.x; acc[r][1] += av * w0.y;
        acc[r][2] += av * w0.z; acc[r][3] += av * w0.w;
        acc[r][4] += av * w1.x; acc[r][5] += av * w1.y;
        acc[r][6] += av * w1.z; acc[r][7] += av * w1.w;
      }
    }
  }

#pragma unroll
  for (int r = 0; r < 8; ++r) {
    int row = row0 + ty * 8 + r;
    if (row < NN) {
      float4 o0 = { acc[r][0], acc[r][1], acc[r][2], acc[r][3] };
      float4 o1 = { acc[r][4], acc[r][5], acc[r][6], acc[r][7] };
      *(float4*)(Cb + (size_t)row * 128 + c0)     = o0;
      *(float4*)(Cb + (size_t)row * 128 + c0 + 4) = o1;
    }
  }
}

// ---------- fused GAT node kernel ----------
// 32 lanes/node, log2-domain logits (exp2), 4-edge blocks with 1-ahead pipeline
__device__ __forceinline__ float edge_logit(float4 msg, float w,
                                            float4 hrd, float4 we4, float4 at4)
{
  // at4 is pre-scaled by 1/ln2, so the returned logit is in log2 domain
  float s0 = lrelu(fmaf(w, we4.x, hrd.x) + msg.x);
  float s1 = lrelu(fmaf(w, we4.y, hrd.y) + msg.y);
  float s2 = lrelu(fmaf(w, we4.z, hrd.z) + msg.z);
  float s3 = lrelu(fmaf(w, we4.w, hrd.w) + msg.w);
  float p = fmaf(s0, at4.x, fmaf(s1, at4.y, fmaf(s2, at4.z, s3 * at4.w)));
  p += __shfl_xor(p, 1, 8);
  p += __shfl_xor(p, 2, 8);
  p += __shfl_xor(p, 4, 8);
  return p;
}

__global__ __launch_bounds__(256) void gat_node_kernel(
    const int* __restrict__ cnt_arr, const int2* __restrict__ pack,
    const float* __restrict__ hl, const float* __restrict__ hr,
    const float* __restrict__ We, const float* __restrict__ att,
    const float* __restrict__ bias, float* __restrict__ out)
{
  int n = blockIdx.x * 8 + (threadIdx.x >> 5);
  if (n >= NN) return;
  int lq = threadIdx.x & 31;
  int j = lq * 4;
  float4 hrd = *(const float4*)(hr + (size_t)n * 128 + j);
  float4 we4 = *(const float4*)(We + j);
  float4 at4 = *(const float4*)(att + j);
  const float RLN2 = 1.44269504088896340736f;
  at4.x *= RLN2; at4.y *= RLN2; at4.z *= RLN2; at4.w *= RLN2;

  int cnt = cnt_arr[n]; if (cnt > CAP) cnt = CAP;
  const int2* p = pack + (size_t)n * CAP;

  float m = -INFINITY, l = 0.f, wsum = 0.f;
  float4 acc = { 0.f, 0.f, 0.f, 0.f };

  int nb = cnt >> 2;
  int4 ca, cb;                     // next block's packed edges (2x int4 = 4x int2)
  float4 nr1, nr2, nr3, nr4;       // next block's gathered rows
  if (nb > 0) {
    const int4* p4 = (const int4*)p;
    ca = p4[0]; cb = p4[1];
    nr1 = *(const float4*)(hl + (size_t)ca.x * 128 + j);
    nr2 = *(const float4*)(hl + (size_t)ca.z * 128 + j);
    nr3 = *(const float4*)(hl + (size_t)cb.x * 128 + j);
    nr4 = *(const float4*)(hl + (size_t)cb.z * 128 + j);
  }
  for (int b = 0; b < nb; ++b) {
    int4 da = ca, db = cb;
    float4 m1 = nr1, m2 = nr2, m3 = nr3, m4 = nr4;
    if (b + 1 < nb) {                       // issue next block's loads now
      const int4* p4 = (const int4*)(p + (b + 1) * 4);
      ca = p4[0]; cb = p4[1];
      nr1 = *(const float4*)(hl + (size_t)ca.x * 128 + j);
      nr2 = *(const float4*)(hl + (size_t)ca.z * 128 + j);
      nr3 = *(const float4*)(hl + (size_t)cb.x * 128 + j);
      nr4 = *(const float4*)(hl + (size_t)cb.z * 128 + j);
    }
    float w1 = __int_as_float(da.y), w2 = __int_as_float(da.w);
    float w3 = __int_as_float(db.y), w4 = __int_as_float(db.w);
    wsum += (w1 + w2) + (w3 + w4);
    float p1 = edge_logit(m1, w1, hrd, we4, at4);
    float p2 = edge_logit(m2, w2, hrd, we4, at4);
    float p3 = edge_logit(m3, w3, hrd, we4, at4);
    float p4v = edge_logit(m4, w4, hrd, we4, at4);
    float mn = fmaxf(fmaxf(m, fmaxf(p1, p2)), fmaxf(p3, p4v));
    float sc = exp2f(m - mn);
    float t1 = exp2f(p1 - mn);
    float t2 = exp2f(p2 - mn);
    float t3 = exp2f(p3 - mn);
    float t4 = exp2f(p4v - mn);
    l = fmaf(l, sc, (t1 + t2) + (t3 + t4));
    acc.x = fmaf(acc.x, sc, fmaf(t1, m1.x, fmaf(t2, m2.x, fmaf(t3, m3.x, t4 * m4.x))));
    acc.y = fmaf(acc.y, sc, fmaf(t1, m1.y, fmaf(t2, m2.y, fmaf(t3, m3.y, t4 * m4.y))));
    acc.z = fmaf(acc.z, sc, fmaf(t1, m1.z, fmaf(t2, m2.z, fmaf(t3, m3.z, t4 * m4.z))));
    acc.w = fmaf(acc.w, sc, fmaf(t1, m1.w, fmaf(t2, m2.w, fmaf(t3, m3.w, t4 * m4.w))));
    m = mn;
  }
  for (int i = nb * 4; i < cnt; ++i) {
    int2 v1 = p[i];
    float w1 = __int_as_float(v1.y);
    float4 m1 = *(const float4*)(hl + (size_t)v1.x * 128 + j);
    wsum += w1;
    float p1 = edge_logit(m1, w1, hrd, we4, at4);
    float mn = fmaxf(m, p1);
    float sc = exp2f(m - mn);
    float t1 = exp2f(p1 - mn);
    l = fmaf(l, sc, t1);
    acc.x = fmaf(acc.x, sc, t1 * m1.x);
    acc.y = fmaf(acc.y, sc, t1 * m1.y);
    acc.z = fmaf(acc.z, sc, t1 * m1.z);
    acc.w = fmaf(acc.w, sc, t1 * m1.w);
  }

  // self-loop with mean edge attr, merged last
  float la = wsum / fmaxf((float)cnt, 1.f);
  float4 msgs = *(const float4*)(hl + (size_t)n * 128 + j);
  float ps = edge_logit(msgs, la, hrd, we4, at4);
  float mn = fmaxf(m, ps);
  float sc = exp2f(m - mn);      // exp2(-inf)=0 when cnt==0
  float ts = exp2f(ps - mn);
  l = fmaf(l, sc, ts);
  acc.x = fmaf(acc.x, sc, ts * msgs.x);
  acc.y = fmaf(acc.y, sc, ts * msgs.y);
  acc.z = fmaf(acc.z, sc, ts * msgs.z);
  acc.w = fmaf(acc.w, sc, ts * msgs.w);

  float inv = 1.f / l;
  float4 b4 = *(const float4*)(bias + j);
  float4 o;
  o.x = fmaxf(fmaf(acc.x, inv, b4.x), 0.f);
  o.y = fmaxf(fmaf(acc.y, inv, b4.y), 0.f);
  o.z = fmaxf(fmaf(acc.z, inv, b4.z), 0.f);
  o.w = fmaxf(fmaf(acc.w, inv, b4.w), 0.f);
  *(float4*)(out + (size_t)n * 128 + j) = o;
}

// ---------- pool (batch is sorted): 64 rows/block ----------
__global__ __launch_bounds__(128) void pool_kernel(
    const float* __restrict__ h, const int* __restrict__ batch,
    float* __restrict__ pooled)
{
  int n0 = blockIdx.x * 64;
  if (n0 >= NN) return;
  int j = threadIdx.x;
  int nend = n0 + 64; if (nend > NN) nend = NN;
  float acc = 0.f;
  int curb = batch[n0];
  for (int n = n0; n < nend; ++n) {
    int b = batch[n];
    if (b != curb) {
      unsafeAtomicAdd(pooled + curb * 128 + j, acc);
      acc = 0.f; curb = b;
    }
    acc += h[(size_t)n * 128 + j];
  }
  unsafeAtomicAdd(pooled + curb * 128 + j, acc);
}

// ---------- fc ----------
__global__ __launch_bounds__(128) void fc_kernel(
    const float* __restrict__ pooled, const float* __restrict__ fcw,
    const float* __restrict__ fcb, float* __restrict__ out)
{
  int b = blockIdx.x;
  int t = threadIdx.x;
  float v = pooled[b * 128 + t] * fcw[t];
#pragma unroll
  for (int off = 32; off >= 1; off >>= 1) v += __shfl_down(v, off, 64);
  __shared__ float sbuf[2];
  if ((t & 63) == 0) sbuf[t >> 6] = v;
  __syncthreads();
  if (t == 0) out[b] = sbuf[0] + sbuf[1] + fcb[0];
}

extern "C" void kernel_launch(void* const* d_in, const int* in_sizes, int n_in,
                              void* d_out, int out_size, void* d_ws, size_t ws_size,
                              hipStream_t stream)
{
  const float* x    = (const float*)d_in[0];
  const int*   ei   = (const int*)d_in[1];
  const float* ea   = (const float*)d_in[2];
  const int*   batch= (const int*)d_in[3];
  const float* c1w  = (const float*)d_in[4];
  const float* c1b  = (const float*)d_in[5];
  const float* c2w  = (const float*)d_in[6];
  const float* c2b  = (const float*)d_in[7];
  const float* gWl[2] = { (const float*)d_in[8],  (const float*)d_in[13] };
  const float* gWr[2] = { (const float*)d_in[9],  (const float*)d_in[14] };
  const float* gWe[2] = { (const float*)d_in[10], (const float*)d_in[15] };
  const float* gAt[2] = { (const float*)d_in[11], (const float*)d_in[16] };
  const float* gB [2] = { (const float*)d_in[12], (const float*)d_in[17] };
  const float* fcw  = (const float*)d_in[18];
  const float* fcb  = (const float*)d_in[19];
  float* out = (float*)d_out;

  const int* src = ei;
  const int* dst = ei + EE;

  float* ws = (float*)d_ws;
  float* h0      = ws;                         // 12,800,000 f
  float* hl      = h0 + 12800000;              // 12,800,000 f
  float* hr      = hl + 12800000;              // 12,800,000 f
  int2*  pack    = (int2*)(hr + 12800000);     // NN*CAP int2
  int*   cursor  = (int*)(pack + (size_t)NN * CAP); // 100,000 i
  float* pooled  = (float*)(cursor + NN);      // 8,192 f

  hipMemsetAsync(cursor, 0, NN * sizeof(int), stream);
  hipMemsetAsync(pooled, 0, BB * 128 * sizeof(float), stream);

  conv_kernel<<<(NN + 15) / 16, 256, 0, stream>>>(x, c1w, c1b, c2w, c2b, h0);
  scatter_pad<<<(EE / 4 + 255) / 256, 256, 0, stream>>>(src, dst, ea, cursor, pack);

  for (int L = 0; L < 2; ++L) {
    gemm_dual<<<(NN + 63) / 64, 256, 0, stream>>>(h0, gWl[L], gWr[L], hl, hr);
    gat_node_kernel<<<(NN + 7) / 8, 256, 0, stream>>>(cursor, pack, hl, hr,
                                                      gWe[L], gAt[L], gB[L], h0);
  }

  pool_kernel<<<(NN + 63) / 64, 128, 0, stream>>>(h0, batch, pooled);
  fc_kernel<<<BB, 128, 0, stream>>>(pooled, fcw, fcb, out);
}

// Round 9
// 764.332 us; speedup vs baseline: 1.0302x; 1.0302x over previous
//
#include <hip/hip_runtime.h>
#include <math.h>

#define NN 100000
#define EE 1600000
#define BB 64
#define CAP 48   // max in-degree; deg ~ Poisson(16), P(deg>=48) ~ 2e-10

#define SCAT_B ((EE + 255) / 256)   // 6250 scatter blocks (first: long pole)
#define CONV_B ((NN + 15) / 16)     // 6250 conv blocks

__device__ __forceinline__ float lrelu(float v) { return v > 0.f ? v : 0.2f * v; }

// ---------- fused: scatter_pad (blocks 0..SCAT_B) + temporal conv (rest) ----------
__global__ __launch_bounds__(256) void conv_scatter_kernel(
    const float* __restrict__ x,
    const float* __restrict__ w1, const float* __restrict__ b1,
    const float* __restrict__ w2, const float* __restrict__ b2,
    float* __restrict__ h0,
    const int* __restrict__ src, const int* __restrict__ dst,
    const float* __restrict__ ea,
    int* __restrict__ cursor, int2* __restrict__ pack)
{
  int tid = threadIdx.x;
  if (blockIdx.x < SCAT_B) {
    // ---- scatter: 1 edge/thread (measured-best shape) ----
    int e = blockIdx.x * 256 + tid;
    if (e >= EE) return;
    int d = dst[e];
    int pos = atomicAdd(cursor + d, 1);
    if (pos < CAP)
      pack[(size_t)d * CAP + pos] = make_int2(src[e], __float_as_int(ea[e]));
    return;
  }
  // ---- conv: 16 nodes/block x 16 threads/node ----
  __shared__ float s_x[16 * 35];
  __shared__ float s_c1[16 * 49];
  __shared__ float s_w2[16 * 49];
  __shared__ float s_w1[48], s_b1[16], s_b2[16];
  int n0 = (blockIdx.x - SCAT_B) * 16;
  for (int i = tid; i < 16 * 35; i += 256) s_x[i] = x[(size_t)n0 * 35 + i];
  if (tid < 48) s_w1[tid] = w1[tid];
  if (tid < 16) { s_b1[tid] = b1[tid]; s_b2[tid] = b2[tid]; }
  for (int i = tid; i < 768; i += 256) s_w2[(i / 48) * 49 + (i % 48)] = w2[i];
  __syncthreads();

  int node = tid >> 4;
  int lane = tid & 15;
  const float* row = s_x + node * 35;
  float* c1n = s_c1 + node * 49;
  float acc8[8];

  for (int t = 0; t < 8; ++t) {
#pragma unroll
    for (int k = 0; k < 3; ++k) {
      int base = 4 * t + 2 * k;
      float a = s_b1[lane] + s_w1[lane * 3] * row[base]
                           + s_w1[lane * 3 + 1] * row[base + 1]
                           + s_w1[lane * 3 + 2] * row[base + 2];
      c1n[lane * 3 + k] = a > 0.f ? a : 0.f;
    }
    __syncthreads();
    float acc = s_b2[lane];
    const float* w2r = s_w2 + lane * 49;
#pragma unroll
    for (int i = 0; i < 48; ++i) acc += w2r[i] * c1n[i];
    acc8[t] = fmaxf(acc, 0.f);
    __syncthreads();
  }

  float* o = h0 + (size_t)(n0 + node) * 128 + lane * 8;
  float4 o0 = { acc8[0], acc8[1], acc8[2], acc8[3] };
  float4 o1 = { acc8[4], acc8[5], acc8[6], acc8[7] };
  *(float4*)o = o0;
  *(float4*)(o + 4) = o1;
}

// ---------- dual GEMM as C = A @ [Wl|Wr]: 64x256 block tile, 8x8 thread tile ----------
__global__ __launch_bounds__(256) void gemm_dual(
    const float* __restrict__ A,
    const float* __restrict__ Wl, const float* __restrict__ Wr,
    float* __restrict__ Cl, float* __restrict__ Cr)
{
  __shared__ float sA[64][128];
  int tid = threadIdx.x;
  int row0 = blockIdx.x * 64;
  int nrows = NN - row0; if (nrows > 64) nrows = 64;
  for (int i = tid; i < nrows * 32; i += 256)
    ((float4*)sA)[i] = ((const float4*)(A + (size_t)row0 * 128))[i];
  __syncthreads();

  int tx = tid & 31;
  int ty = tid >> 5;
  const float* Wb = (tx < 16) ? Wl : Wr;
  float*       Cb = (tx < 16) ? Cl : Cr;
  int c0 = (tx & 15) * 8;

  float acc[8][8];
#pragma unroll
  for (int r = 0; r < 8; ++r)
#pragma unroll
    for (int c = 0; c < 8; ++c) acc[r][c] = 0.f;

  for (int k = 0; k < 128; k += 4) {
    float4 a[8];
#pragma unroll
    for (int r = 0; r < 8; ++r) a[r] = *(const float4*)&sA[ty * 8 + r][k];
#pragma unroll
    for (int kk = 0; kk < 4; ++kk) {
      float4 w0 = *(const float4*)&Wb[(k + kk) * 128 + c0];
      float4 w1 = *(const float4*)&Wb[(k + kk) * 128 + c0 + 4];
#pragma unroll
      for (int r = 0; r < 8; ++r) {
        float av = (kk == 0) ? a[r].x : (kk == 1) ? a[r].y : (kk == 2) ? a[r].z : a[r].w;
        acc[r][0] += av * w0.x; acc[r][1] += av * w0.y;
        acc[r][2] += av * w0.z; acc[r][3] += av * w0.w;
        acc[r][4] += av * w1.x; acc[r][5] += av * w1.y;
        acc[r][6] += av * w1.z; acc[r][7] += av * w1.w;
      }
    }
  }

#pragma unroll
  for (int r = 0; r < 8; ++r) {
    int row = row0 + ty * 8 + r;
    if (row < NN) {
      float4 o0 = { acc[r][0], acc[r][1], acc[r][2], acc[r][3] };
      float4 o1 = { acc[r][4], acc[r][5], acc[r][6], acc[r][7] };
      *(float4*)(Cb + (size_t)row * 128 + c0)     = o0;
      *(float4*)(Cb + (size_t)row * 128 + c0 + 4) = o1;
    }
  }
}

// ---------- fused GAT node kernel ----------
// 32 lanes/node, log2-domain logits (exp2), 4-edge blocks with 1-ahead pipeline
__device__ __forceinline__ float edge_logit(float4 msg, float w,
                                            float4 hrd, float4 we4, float4 at4)
{
  // at4 pre-scaled by 1/ln2 -> logit in log2 domain
  float s0 = lrelu(fmaf(w, we4.x, hrd.x) + msg.x);
  float s1 = lrelu(fmaf(w, we4.y, hrd.y) + msg.y);
  float s2 = lrelu(fmaf(w, we4.z, hrd.z) + msg.z);
  float s3 = lrelu(fmaf(w, we4.w, hrd.w) + msg.w);
  float p = fmaf(s0, at4.x, fmaf(s1, at4.y, fmaf(s2, at4.z, s3 * at4.w)));
  p += __shfl_xor(p, 1, 8);
  p += __shfl_xor(p, 2, 8);
  p += __shfl_xor(p, 4, 8);
  return p;
}

__global__ __launch_bounds__(256) void gat_node_kernel(
    const int* __restrict__ cnt_arr, const int2* __restrict__ pack,
    const float* __restrict__ hl, const float* __restrict__ hr,
    const float* __restrict__ We, const float* __restrict__ att,
    const float* __restrict__ bias, float* __restrict__ out)
{
  int n = blockIdx.x * 8 + (threadIdx.x >> 5);
  if (n >= NN) return;
  int lq = threadIdx.x & 31;
  int j = lq * 4;
  float4 hrd = *(const float4*)(hr + (size_t)n * 128 + j);
  float4 we4 = *(const float4*)(We + j);
  float4 at4 = *(const float4*)(att + j);
  const float RLN2 = 1.44269504088896340736f;
  at4.x *= RLN2; at4.y *= RLN2; at4.z *= RLN2; at4.w *= RLN2;

  int cnt = cnt_arr[n]; if (cnt > CAP) cnt = CAP;
  const int2* p = pack + (size_t)n * CAP;

  float m = -INFINITY, l = 0.f, wsum = 0.f;
  float4 acc = { 0.f, 0.f, 0.f, 0.f };

  int nb = cnt >> 2;
  int4 ca, cb;
  float4 nr1, nr2, nr3, nr4;
  if (nb > 0) {
    const int4* p4 = (const int4*)p;
    ca = p4[0]; cb = p4[1];
    nr1 = *(const float4*)(hl + (size_t)ca.x * 128 + j);
    nr2 = *(const float4*)(hl + (size_t)ca.z * 128 + j);
    nr3 = *(const float4*)(hl + (size_t)cb.x * 128 + j);
    nr4 = *(const float4*)(hl + (size_t)cb.z * 128 + j);
  }
  for (int b = 0; b < nb; ++b) {
    int4 da = ca, db = cb;
    float4 m1 = nr1, m2 = nr2, m3 = nr3, m4 = nr4;
    if (b + 1 < nb) {
      const int4* p4 = (const int4*)(p + (b + 1) * 4);
      ca = p4[0]; cb = p4[1];
      nr1 = *(const float4*)(hl + (size_t)ca.x * 128 + j);
      nr2 = *(const float4*)(hl + (size_t)ca.z * 128 + j);
      nr3 = *(const float4*)(hl + (size_t)cb.x * 128 + j);
      nr4 = *(const float4*)(hl + (size_t)cb.z * 128 + j);
    }
    float w1 = __int_as_float(da.y), w2 = __int_as_float(da.w);
    float w3 = __int_as_float(db.y), w4 = __int_as_float(db.w);
    wsum += (w1 + w2) + (w3 + w4);
    float p1 = edge_logit(m1, w1, hrd, we4, at4);
    float p2 = edge_logit(m2, w2, hrd, we4, at4);
    float p3 = edge_logit(m3, w3, hrd, we4, at4);
    float p4v = edge_logit(m4, w4, hrd, we4, at4);
    float mn = fmaxf(fmaxf(m, fmaxf(p1, p2)), fmaxf(p3, p4v));
    float sc = exp2f(m - mn);
    float t1 = exp2f(p1 - mn);
    float t2 = exp2f(p2 - mn);
    float t3 = exp2f(p3 - mn);
    float t4 = exp2f(p4v - mn);
    l = fmaf(l, sc, (t1 + t2) + (t3 + t4));
    acc.x = fmaf(acc.x, sc, fmaf(t1, m1.x, fmaf(t2, m2.x, fmaf(t3, m3.x, t4 * m4.x))));
    acc.y = fmaf(acc.y, sc, fmaf(t1, m1.y, fmaf(t2, m2.y, fmaf(t3, m3.y, t4 * m4.y))));
    acc.z = fmaf(acc.z, sc, fmaf(t1, m1.z, fmaf(t2, m2.z, fmaf(t3, m3.z, t4 * m4.z))));
    acc.w = fmaf(acc.w, sc, fmaf(t1, m1.w, fmaf(t2, m2.w, fmaf(t3, m3.w, t4 * m4.w))));
    m = mn;
  }
  for (int i = nb * 4; i < cnt; ++i) {
    int2 v1 = p[i];
    float w1 = __int_as_float(v1.y);
    float4 m1 = *(const float4*)(hl + (size_t)v1.x * 128 + j);
    wsum += w1;
    float p1 = edge_logit(m1, w1, hrd, we4, at4);
    float mn = fmaxf(m, p1);
    float sc = exp2f(m - mn);
    float t1 = exp2f(p1 - mn);
    l = fmaf(l, sc, t1);
    acc.x = fmaf(acc.x, sc, t1 * m1.x);
    acc.y = fmaf(acc.y, sc, t1 * m1.y);
    acc.z = fmaf(acc.z, sc, t1 * m1.z);
    acc.w = fmaf(acc.w, sc, t1 * m1.w);
  }

  float la = wsum / fmaxf((float)cnt, 1.f);
  float4 msgs = *(const float4*)(hl + (size_t)n * 128 + j);
  float ps = edge_logit(msgs, la, hrd, we4, at4);
  float mn = fmaxf(m, ps);
  float sc = exp2f(m - mn);
  float ts = exp2f(ps - mn);
  l = fmaf(l, sc, ts);
  acc.x = fmaf(acc.x, sc, ts * msgs.x);
  acc.y = fmaf(acc.y, sc, ts * msgs.y);
  acc.z = fmaf(acc.z, sc, ts * msgs.z);
  acc.w = fmaf(acc.w, sc, ts * msgs.w);

  float inv = 1.f / l;
  float4 b4 = *(const float4*)(bias + j);
  float4 o;
  o.x = fmaxf(fmaf(acc.x, inv, b4.x), 0.f);
  o.y = fmaxf(fmaf(acc.y, inv, b4.y), 0.f);
  o.z = fmaxf(fmaf(acc.z, inv, b4.z), 0.f);
  o.w = fmaxf(fmaf(acc.w, inv, b4.w), 0.f);
  *(float4*)(out + (size_t)n * 128 + j) = o;
}

// ---------- pool (batch is sorted): 64 rows/block ----------
__global__ __launch_bounds__(128) void pool_kernel(
    const float* __restrict__ h, const int* __restrict__ batch,
    float* __restrict__ pooled)
{
  int n0 = blockIdx.x * 64;
  if (n0 >= NN) return;
  int j = threadIdx.x;
  int nend = n0 + 64; if (nend > NN) nend = NN;
  float acc = 0.f;
  int curb = batch[n0];
  for (int n = n0; n < nend; ++n) {
    int b = batch[n];
    if (b != curb) {
      unsafeAtomicAdd(pooled + curb * 128 + j, acc);
      acc = 0.f; curb = b;
    }
    acc += h[(size_t)n * 128 + j];
  }
  unsafeAtomicAdd(pooled + curb * 128 + j, acc);
}

// ---------- fc ----------
__global__ __launch_bounds__(128) void fc_kernel(
    const float* __restrict__ pooled, const float* __restrict__ fcw,
    const float* __restrict__ fcb, float* __restrict__ out)
{
  int b = blockIdx.x;
  int t = threadIdx.x;
  float v = pooled[b * 128 + t] * fcw[t];
#pragma unroll
  for (int off = 32; off >= 1; off >>= 1) v += __shfl_down(v, off, 64);
  __shared__ float sbuf[2];
  if ((t & 63) == 0) sbuf[t >> 6] = v;
  __syncthreads();
  if (t == 0) out[b] = sbuf[0] + sbuf[1] + fcb[0];
}

extern "C" void kernel_launch(void* const* d_in, const int* in_sizes, int n_in,
                              void* d_out, int out_size, void* d_ws, size_t ws_size,
                              hipStream_t stream)
{
  const float* x    = (const float*)d_in[0];
  const int*   ei   = (const int*)d_in[1];
  const float* ea   = (const float*)d_in[2];
  const int*   batch= (const int*)d_in[3];
  const float* c1w  = (const float*)d_in[4];
  const float* c1b  = (const float*)d_in[5];
  const float* c2w  = (const float*)d_in[6];
  const float* c2b  = (const float*)d_in[7];
  const float* gWl[2] = { (const float*)d_in[8],  (const float*)d_in[13] };
  const float* gWr[2] = { (const float*)d_in[9],  (const float*)d_in[14] };
  const float* gWe[2] = { (const float*)d_in[10], (const float*)d_in[15] };
  const float* gAt[2] = { (const float*)d_in[11], (const float*)d_in[16] };
  const float* gB [2] = { (const float*)d_in[12], (const float*)d_in[17] };
  const float* fcw  = (const float*)d_in[18];
  const float* fcb  = (const float*)d_in[19];
  float* out = (float*)d_out;

  const int* src = ei;
  const int* dst = ei + EE;

  float* ws = (float*)d_ws;
  float* h0      = ws;                         // 12,800,000 f
  float* hl      = h0 + 12800000;              // 12,800,000 f
  float* hr      = hl + 12800000;              // 12,800,000 f
  int2*  pack    = (int2*)(hr + 12800000);     // NN*CAP int2
  int*   cursor  = (int*)(pack + (size_t)NN * CAP); // 100,000 i
  float* pooled  = (float*)(cursor + NN);      // 8,192 f

  hipMemsetAsync(cursor, 0, NN * sizeof(int), stream);
  hipMemsetAsync(pooled, 0, BB * 128 * sizeof(float), stream);

  conv_scatter_kernel<<<SCAT_B + CONV_B, 256, 0, stream>>>(
      x, c1w, c1b, c2w, c2b, h0, src, dst, ea, cursor, pack);

  for (int L = 0; L < 2; ++L) {
    gemm_dual<<<(NN + 63) / 64, 256, 0, stream>>>(h0, gWl[L], gWr[L], hl, hr);
    gat_node_kernel<<<(NN + 7) / 8, 256, 0, stream>>>(cursor, pack, hl, hr,
                                                      gWe[L], gAt[L], gB[L], h0);
  }

  pool_kernel<<<(NN + 63) / 64, 128, 0, stream>>>(h0, batch, pooled);
  fc_kernel<<<BB, 128, 0, stream>>>(pooled, fcw, fcb, out);
}